// Round 10
// baseline (280.730 us; speedup 1.0000x reference)
//
#include <hip/hip_runtime.h>
#include <math.h>

namespace {
constexpr int NB = 4;       // batch
constexpr int NN = 2048;    // sequence
constexpr int FD = 1024;    // feature dim
constexpr int DE = 128;     // energy dim
constexpr int BN = NB * NN; // 8192 rows total

// ---- workspace layout (f32 units).
// Phase A:
//   [0 .. 262,144)             Wsw: Wqh,Wql,Wkh,Wkl frag-tiled (4 x 131,072 ushort)
//   [8,388,608 .. 12,582,912)  Fh_sw (8.4M ushort, frag-tiled)
//   [12,582,912 .. 16,777,216) Fl_sw
//   [16,777,216 .. 18,874,368) Qh,Ql,Kh,Kl frag-tiled bf16 (4 x 1,048,576 ushort)
// Step phase:
//   baseH (f16 [4][2048][2048] = 8,388,608 f32) overlays [0..8,388,608)
//   P[1024][2048] f32 overlays the dead Fh region at FH_OFF.
constexpr size_t WSW_OFF   = 0;
constexpr size_t FH_OFF    = 8388608;
constexpr size_t FL_OFF    = 12582912;
constexpr size_t QKHL_OFF  = 16777216;
constexpr size_t C_OFF     = QKHL_OFF + 2097152;   // 5 x [BN] charges
}

typedef __attribute__((ext_vector_type(8))) short bf16x8;
typedef __attribute__((ext_vector_type(4))) float f32x4;
typedef __attribute__((ext_vector_type(8))) _Float16 f16x8;

__device__ __forceinline__ unsigned short bf16_hi(float x) {
    unsigned u = __float_as_uint(x);
    unsigned r = (u + 0x7fffu + ((u >> 16) & 1u)) >> 16;
    return (unsigned short)r;
}
__device__ __forceinline__ float bf16_val(unsigned short h) {
    return __uint_as_float((unsigned)h << 16);
}

// Frag-tile layout: tile(row0=16 rows, k0=32 k) -> 64 lanes x 8 bf16, 1KB
// contiguous. lane = quad*16 + l16 holds (row = row0+l16, k = k0+quad*8+j).

// ---------------------------------------------------------------------------
// PREP (fused): blocks [0,4096) convert_F; [4096,4224) convert_W;
// [4224,6272) charge_init.
__global__ __launch_bounds__(256) void prep(
        const float* __restrict__ feat, const float* __restrict__ Wq,
        const float* __restrict__ Wk, const float* __restrict__ cw,
        const float* __restrict__ cbias,
        unsigned short* __restrict__ Fh, unsigned short* __restrict__ Fl,
        unsigned short* __restrict__ Wqh, unsigned short* __restrict__ Wql,
        unsigned short* __restrict__ Wkh, unsigned short* __restrict__ Wkl,
        float* __restrict__ c0) {
    const int bid = blockIdx.x;
    const int tid = threadIdx.x;
    if (bid < 4096) {
        const int g = bid * 256 + tid;
        const int tile = g >> 6, lane = g & 63;
        const int tr = tile >> 5, fc = tile & 31;
        const int row = tr * 16 + (lane & 15);
        const int f0 = fc * 32 + (lane >> 4) * 8;
        const float* src = &feat[(size_t)row * FD + f0];
        ushort4 h0, l0, h1, l1;
        float4 a = *(const float4*)src;
        float4 b = *(const float4*)(src + 4);
        h0.x = bf16_hi(a.x); l0.x = bf16_hi(a.x - bf16_val(h0.x));
        h0.y = bf16_hi(a.y); l0.y = bf16_hi(a.y - bf16_val(h0.y));
        h0.z = bf16_hi(a.z); l0.z = bf16_hi(a.z - bf16_val(h0.z));
        h0.w = bf16_hi(a.w); l0.w = bf16_hi(a.w - bf16_val(h0.w));
        h1.x = bf16_hi(b.x); l1.x = bf16_hi(b.x - bf16_val(h1.x));
        h1.y = bf16_hi(b.y); l1.y = bf16_hi(b.y - bf16_val(h1.y));
        h1.z = bf16_hi(b.z); l1.z = bf16_hi(b.z - bf16_val(h1.z));
        h1.w = bf16_hi(b.w); l1.w = bf16_hi(b.w - bf16_val(h1.w));
        const size_t dst = (size_t)tile * 512 + lane * 8;
        *(ushort4*)&Fh[dst] = h0; *(ushort4*)&Fh[dst + 4] = h1;
        *(ushort4*)&Fl[dst] = l0; *(ushort4*)&Fl[dst + 4] = l1;
    } else if (bid < 4224) {
        const int wbid = bid - 4096;
        const int mat = wbid >> 6;
        const int g = (wbid & 63) * 256 + tid;
        const int tile = g >> 6, lane = g & 63;
        const int ec = tile >> 5, fc = tile & 31;
        const int e = ec * 16 + (lane & 15);
        const int f0 = fc * 32 + (lane >> 4) * 8;
        const float* W = mat ? Wk : Wq;
        unsigned short* Th = mat ? Wkh : Wqh;
        unsigned short* Tl = mat ? Wkl : Wql;
        unsigned short hh[8], ll[8];
        #pragma unroll
        for (int j = 0; j < 8; ++j) {
            float v = W[(size_t)(f0 + j) * DE + e];
            hh[j] = bf16_hi(v); ll[j] = bf16_hi(v - bf16_val(hh[j]));
        }
        const size_t dst = (size_t)tile * 512 + lane * 8;
        *(ushort4*)&Th[dst]     = make_ushort4(hh[0], hh[1], hh[2], hh[3]);
        *(ushort4*)&Th[dst + 4] = make_ushort4(hh[4], hh[5], hh[6], hh[7]);
        *(ushort4*)&Tl[dst]     = make_ushort4(ll[0], ll[1], ll[2], ll[3]);
        *(ushort4*)&Tl[dst + 4] = make_ushort4(ll[4], ll[5], ll[6], ll[7]);
    } else {
        const int wave = tid >> 6, lane = tid & 63;
        const int r = (bid - 4224) * 4 + wave;
        const float* fr = feat + (size_t)r * FD;
        float s = 0.f;
        #pragma unroll
        for (int k = 0; k < 16; ++k) { int f = lane + 64 * k; s += fr[f] * cw[f]; }
        for (int off = 32; off > 0; off >>= 1) s += __shfl_xor(s, off);
        if (lane == 0) {
            float x = s + cbias[0];
            c0[r] = 1.f / (1.f + __expf(-x));
        }
    }
}

// ---------------------------------------------------------------------------
// QK_PROJ v2 (proven round 9): full-K GEMM with IN-BLOCK 4-way K-split.
__global__ __launch_bounds__(1024) void qk_proj(
        const unsigned short* __restrict__ Fh, const unsigned short* __restrict__ Fl,
        const unsigned short* __restrict__ Wqh, const unsigned short* __restrict__ Wql,
        const unsigned short* __restrict__ Wkh, const unsigned short* __restrict__ Wkl,
        unsigned short* __restrict__ Qh, unsigned short* __restrict__ Ql,
        unsigned short* __restrict__ Kh, unsigned short* __restrict__ Kl) {
    __shared__ f32x4 stage[4096];          // 64KB; first 16KB reused for bf16 out
    const int tid = threadIdx.x;
    const int w = tid >> 6, lane = tid & 63;
    const int quad = lane >> 4, l16 = lane & 15;
    const int blk = blockIdx.x;            // row-tile index (16 rows)
    const int mat = w >> 3, ech = (w >> 2) & 1, kch = w & 3;
    const unsigned short* Bh = mat ? Wkh : Wqh;
    const unsigned short* Bl = mat ? Wkl : Wql;

    f32x4 acc[4];
    #pragma unroll
    for (int c = 0; c < 4; ++c) acc[c] = (f32x4){0.f, 0.f, 0.f, 0.f};

    const int fc0 = kch * 8;
    #pragma unroll 2
    for (int f = 0; f < 8; ++f) {
        const int fc = fc0 + f;
        const size_t aoff = ((size_t)(blk * 32 + fc) * 64 + lane) * 8;
        bf16x8 aH = *(const bf16x8*)&Fh[aoff];
        bf16x8 aL = *(const bf16x8*)&Fl[aoff];
        #pragma unroll
        for (int ct = 0; ct < 4; ++ct) {
            const size_t boff = ((size_t)((ech * 4 + ct) * 32 + fc) * 64 + lane) * 8;
            bf16x8 bH = *(const bf16x8*)&Bh[boff];
            bf16x8 bL = *(const bf16x8*)&Bl[boff];
            acc[ct] = __builtin_amdgcn_mfma_f32_16x16x32_bf16(aH, bH, acc[ct], 0, 0, 0);
            acc[ct] = __builtin_amdgcn_mfma_f32_16x16x32_bf16(aH, bL, acc[ct], 0, 0, 0);
            acc[ct] = __builtin_amdgcn_mfma_f32_16x16x32_bf16(aL, bH, acc[ct], 0, 0, 0);
        }
    }
    #pragma unroll
    for (int ct = 0; ct < 4; ++ct)
        stage[(w * 4 + ct) * 64 + lane] = acc[ct];
    __syncthreads();

    f32x4 red[4];
    const bool reducer = (kch == 0);
    if (reducer) {
        #pragma unroll
        for (int ct = 0; ct < 4; ++ct) {
            f32x4 s = stage[(w * 4 + ct) * 64 + lane];
            #pragma unroll
            for (int k = 1; k < 4; ++k) {
                const f32x4 t = stage[((w + k) * 4 + ct) * 64 + lane];
                s.x += t.x; s.y += t.y; s.z += t.z; s.w += t.w;
            }
            red[ct] = s;
        }
    }
    __syncthreads();

    unsigned short* lds16 = (unsigned short*)stage;
    if (reducer) {
        #pragma unroll
        for (int ct = 0; ct < 4; ++ct) {
            const int e = (ech * 4 + ct) * 16 + l16;
            const int kce = e >> 5, q2 = (e >> 3) & 3, j2 = e & 7;
            #pragma unroll
            for (int reg = 0; reg < 4; ++reg) {
                const int rl = quad * 4 + reg;
                const float v = red[ct][reg];
                const unsigned short h = bf16_hi(v);
                const unsigned short l = bf16_hi(v - bf16_val(h));
                const int idx = (kce * 64 + q2 * 16 + rl) * 8 + j2;
                lds16[(mat * 2 + 0) * 2048 + idx] = h;
                lds16[(mat * 2 + 1) * 2048 + idx] = l;
            }
        }
    }
    __syncthreads();

    const int ch = tid >> 8, o = (tid & 255) * 8;
    const size_t gbase = (size_t)blk * 2048;
    unsigned short* const dsts[4] = {Qh, Ql, Kh, Kl};
    unsigned short* dst = dsts[ch] + gbase + o;
    *(ushort4*)&dst[0] = *(const ushort4*)&lds16[ch * 2048 + o];
    *(ushort4*)&dst[4] = *(const ushort4*)&lds16[ch * 2048 + o + 4];
}

// ---------------------------------------------------------------------------
// K1: baseH = f16((Q.K^T)/sqrt(128) + locality).
__global__ __launch_bounds__(256) void base_mfma(
        const unsigned short* __restrict__ Qh, const unsigned short* __restrict__ Ql,
        const unsigned short* __restrict__ Kh, const unsigned short* __restrict__ Kl,
        const float* __restrict__ d_ls, _Float16* __restrict__ baseH) {
    const int tid = threadIdx.x;
    const int w = tid >> 6, lane = tid & 63;
    const int quad = lane >> 4, l16 = lane & 15;
    const int b = blockIdx.z;
    const int i0 = blockIdx.y * 128, j0 = blockIdx.x * 128;
    const int trA0 = (b * NN + i0) / 16 + w * 2;
    const int trB0 = (b * NN + j0) / 16;

    f32x4 acc[2][8];
    #pragma unroll
    for (int a = 0; a < 2; ++a)
        #pragma unroll
        for (int c = 0; c < 8; ++c) acc[a][c] = (f32x4){0.f, 0.f, 0.f, 0.f};

    #pragma unroll
    for (int kc = 0; kc < 4; ++kc) {
        bf16x8 aH[2], aL[2];
        #pragma unroll
        for (int rt = 0; rt < 2; ++rt) {
            const size_t off = ((size_t)((trA0 + rt) * 4 + kc) * 64 + lane) * 8;
            aH[rt] = *(const bf16x8*)&Qh[off];
            aL[rt] = *(const bf16x8*)&Ql[off];
        }
        #pragma unroll
        for (int ct = 0; ct < 8; ++ct) {
            const size_t off = ((size_t)((trB0 + ct) * 4 + kc) * 64 + lane) * 8;
            bf16x8 bH = *(const bf16x8*)&Kh[off];
            bf16x8 bL = *(const bf16x8*)&Kl[off];
            #pragma unroll
            for (int rt = 0; rt < 2; ++rt) {
                acc[rt][ct] = __builtin_amdgcn_mfma_f32_16x16x32_bf16(aH[rt], bH, acc[rt][ct], 0, 0, 0);
                acc[rt][ct] = __builtin_amdgcn_mfma_f32_16x16x32_bf16(aH[rt], bL, acc[rt][ct], 0, 0, 0);
                acc[rt][ct] = __builtin_amdgcn_mfma_f32_16x16x32_bf16(aL[rt], bH, acc[rt][ct], 0, 0, 0);
            }
        }
    }
    const float ls = d_ls[0];
    const float rs = 0.08838834764831845f;  // 1/sqrt(128)
    #pragma unroll
    for (int rt = 0; rt < 2; ++rt)
        #pragma unroll
        for (int reg = 0; reg < 4; ++reg) {
            const int i = i0 + w * 32 + rt * 16 + quad * 4 + reg;
            _Float16* brow = baseH + ((size_t)b * NN + i) * NN;
            #pragma unroll
            for (int ct = 0; ct < 8; ++ct) {
                const int j = j0 + ct * 16 + l16;
                const float dist = fmaxf(fabsf((float)(i - j)), 1.0f);
                brow[j] = (_Float16)(acc[rt][ct][reg] * rs + ls / dist);
            }
        }
}

// ---------------------------------------------------------------------------
// K2 v5: 8 cols/thread (proven), restructured to ONE barrier per block.
//  Phase 0: preload ALL 8 rows' base values (8 loads in flight, MLP depth 8)
//           + all row charges + column charges.
//  Phase 1: all 8 rows' partial sums (exp, discarded) -> wsum[8][4]; 1 sync.
//  Phase 2: recompute exp(hv*m)*inv per row -> out / col_acc. Exp recompute
//           costs ~5us VALU across the pass (VALUBusy was 12% -- headroom);
//           buys prefetch depth 8 and kills 7 of 8 barriers.
template <int T, bool WO>
__global__ __launch_bounds__(256) void step_pass(
        const _Float16* __restrict__ base, const float* __restrict__ charge,
        const float* __restrict__ d_ss, float* __restrict__ P,
        float* __restrict__ out) {
    constexpr int TS = T > 0 ? T : 1;
    __shared__ float wsum[8][4];
    const int tid = threadIdx.x;
    const int w = tid >> 6, lane = tid & 63;
    const int blk = blockIdx.x;
    const int b = blk >> 8;               // 256 blocks per batch
    const int r0 = (blk & 255) * 8;       // 8 rows per block
    const float ss = d_ss[0];
    const size_t cb = (size_t)b << 11;
    const int c0 = tid * 8;               // this thread's 8 columns

    // preload all 8 rows of base (independent loads, deep MLP)
    const _Float16* bp = base + (cb + r0) * NN + c0;
    f16x8 hv[8];
    #pragma unroll
    for (int r = 0; r < 8; ++r)
        hv[r] = *(const f16x8*)(bp + (size_t)r * NN);

    // column charges (reused across all 8 rows)
    float cjv[TS][8];
    #pragma unroll
    for (int u = 0; u < T; ++u) {
        const float* s = &charge[(size_t)(u + 1) * BN + cb + c0];
        const float4 a0 = *(const float4*)&s[0];
        const float4 a1 = *(const float4*)&s[4];
        cjv[u][0] = a0.x; cjv[u][1] = a0.y; cjv[u][2] = a0.z; cjv[u][3] = a0.w;
        cjv[u][4] = a1.x; cjv[u][5] = a1.y; cjv[u][6] = a1.z; cjv[u][7] = a1.w;
    }
    // row charges for all 8 rows
    float ci[8][TS];
    #pragma unroll
    for (int r = 0; r < 8; ++r)
        #pragma unroll
        for (int u = 0; u < T; ++u)
            ci[r][u] = charge[(size_t)(u + 1) * BN + cb + r0 + r] * ss;

    // phase 1: partial sums for all 8 rows
    #pragma unroll
    for (int r = 0; r < 8; ++r) {
        float ps = 0.f;
        #pragma unroll
        for (int j = 0; j < 8; ++j) {
            float m = 1.f;
            #pragma unroll
            for (int u = 0; u < T; ++u) m += ci[r][u] * cjv[u][j];
            ps += __expf((float)hv[r][j] * m);
        }
        #pragma unroll
        for (int off = 32; off > 0; off >>= 1) ps += __shfl_xor(ps, off);
        if (lane == 0) wsum[r][w] = ps;
    }
    __syncthreads();   // the ONE barrier

    // phase 2: recompute normalized values, emit
    float col_acc[8];
    if (!WO) {
        #pragma unroll
        for (int j = 0; j < 8; ++j) col_acc[j] = 0.f;
    }
    #pragma unroll
    for (int r = 0; r < 8; ++r) {
        const float inv = 1.f / (wsum[r][0] + wsum[r][1] +
                                 wsum[r][2] + wsum[r][3]);
        float x[8];
        #pragma unroll
        for (int j = 0; j < 8; ++j) {
            float m = 1.f;
            #pragma unroll
            for (int u = 0; u < T; ++u) m += ci[r][u] * cjv[u][j];
            x[j] = __expf((float)hv[r][j] * m) * inv;
        }
        if (WO) {
            float* op = &out[(cb + r0 + r) * NN + c0];
            float4 o0 = {x[0], x[1], x[2], x[3]};
            float4 o1 = {x[4], x[5], x[6], x[7]};
            *(float4*)&op[0] = o0;
            *(float4*)&op[4] = o1;
        } else {
            #pragma unroll
            for (int j = 0; j < 8; ++j) col_acc[j] += x[j];
        }
    }

    if (!WO) {
        float* prow = P + (size_t)blk * NN + c0;
        *(float4*)&prow[0] = *(float4*)&col_acc[0];
        *(float4*)&prow[4] = *(float4*)&col_acc[4];
    }
}

// ---------------------------------------------------------------------------
// K3: received[col] = sum over 256 block partials; charge update.
__global__ __launch_bounds__(256) void charge_reduce(
        const float* __restrict__ P, const float* __restrict__ d_decay,
        const float* __restrict__ c_prev, float* __restrict__ c_next) {
    const int b = blockIdx.x >> 3;
    const int col = ((blockIdx.x & 7) << 8) + threadIdx.x;
    const float* p = P + ((size_t)b * 256) * NN + col;
    float s = 0.f;
    #pragma unroll 8
    for (int r = 0; r < 256; ++r) s += p[(size_t)r * NN];
    const int gi = (b << 11) + col;
    const float sg = 1.f / (1.f + __expf(1.f - s));
    c_next[gi] = c_prev[gi] * (1.f - d_decay[0] * sg);
}

// ---------------------------------------------------------------------------
extern "C" void kernel_launch(void* const* d_in, const int* in_sizes, int n_in,
                              void* d_out, int out_size, void* d_ws, size_t ws_size,
                              hipStream_t stream) {
    const float* feat  = (const float*)d_in[0];
    const float* Wq    = (const float*)d_in[1];
    const float* Wk    = (const float*)d_in[2];
    const float* cw    = (const float*)d_in[3];
    const float* cb    = (const float*)d_in[4];
    const float* ls    = (const float*)d_in[5];
    const float* ssp   = (const float*)d_in[6];
    const float* decay = (const float*)d_in[7];

    float* ws   = (float*)d_ws;
    unsigned short* Fh = (unsigned short*)(ws + FH_OFF);
    unsigned short* Fl = (unsigned short*)(ws + FL_OFF);
    unsigned short* qkhl = (unsigned short*)(ws + QKHL_OFF);
    unsigned short* Qh = qkhl;
    unsigned short* Ql = qkhl + (size_t)BN * DE;
    unsigned short* Kh = qkhl + (size_t)2 * BN * DE;
    unsigned short* Kl = qkhl + (size_t)3 * BN * DE;
    unsigned short* Wqh = (unsigned short*)(ws + WSW_OFF);
    unsigned short* Wql = Wqh + (size_t)DE * FD;
    unsigned short* Wkh = Wqh + (size_t)2 * DE * FD;
    unsigned short* Wkl = Wqh + (size_t)3 * DE * FD;
    float* charge = ws + C_OFF;
    _Float16* baseH = (_Float16*)(ws + WSW_OFF);
    float* P      = ws + FH_OFF;
    float* out    = (float*)d_out;

    prep<<<6272, 256, 0, stream>>>(feat, Wq, Wk, cw, cb,
                                   Fh, Fl, Wqh, Wql, Wkh, Wkl, charge);
    qk_proj<<<512, 1024, 0, stream>>>(Fh, Fl, Wqh, Wql, Wkh, Wkl,
                                      Qh, Ql, Kh, Kl);
    base_mfma<<<dim3(NN / 128, NN / 128, NB), 256, 0, stream>>>(
        Qh, Ql, Kh, Kl, ls, baseH);

    step_pass<0, false><<<1024, 256, 0, stream>>>(baseH, charge, ssp, P, nullptr);
    charge_reduce<<<32, 256, 0, stream>>>(P, decay, charge, charge + (size_t)BN);
    step_pass<1, false><<<1024, 256, 0, stream>>>(baseH, charge, ssp, P, nullptr);
    charge_reduce<<<32, 256, 0, stream>>>(P, decay, charge + (size_t)BN, charge + (size_t)2 * BN);
    step_pass<2, false><<<1024, 256, 0, stream>>>(baseH, charge, ssp, P, nullptr);
    charge_reduce<<<32, 256, 0, stream>>>(P, decay, charge + (size_t)2 * BN, charge + (size_t)3 * BN);
    step_pass<3, false><<<1024, 256, 0, stream>>>(baseH, charge, ssp, P, nullptr);
    charge_reduce<<<32, 256, 0, stream>>>(P, decay, charge + (size_t)3 * BN, charge + (size_t)4 * BN);
    step_pass<4, true><<<1024, 256, 0, stream>>>(baseH, charge, ssp, nullptr, out);
}

// Round 11
// 265.836 us; speedup vs baseline: 1.0560x; 1.0560x over previous
//
#include <hip/hip_runtime.h>
#include <math.h>

namespace {
constexpr int NB = 4;       // batch
constexpr int NN = 2048;    // sequence
constexpr int FD = 1024;    // feature dim
constexpr int DE = 128;     // energy dim
constexpr int BN = NB * NN; // 8192 rows total

// ---- workspace layout (f32 units).
// Phase A:
//   [0 .. 262,144)             Wsw: Wqh,Wql,Wkh,Wkl frag-tiled (4 x 131,072 ushort)
//   [16,777,216 .. 18,874,368) Qh,Ql,Kh,Kl frag-tiled bf16 (4 x 1,048,576 ushort)
// Step phase:
//   baseH (f16 [4][2048][2048] = 8,388,608 f32) overlays [0..8,388,608)
//   P[1024][2048] f32 at FH_OFF (dead region).
constexpr size_t WSW_OFF   = 0;
constexpr size_t FH_OFF    = 8388608;
constexpr size_t QKHL_OFF  = 16777216;
constexpr size_t C_OFF     = QKHL_OFF + 2097152;   // 5 x [BN] charges
}

typedef __attribute__((ext_vector_type(8))) short bf16x8;
typedef __attribute__((ext_vector_type(4))) float f32x4;
typedef __attribute__((ext_vector_type(8))) _Float16 f16x8;

__device__ __forceinline__ unsigned short bf16_hi(float x) {
    unsigned u = __float_as_uint(x);
    unsigned r = (u + 0x7fffu + ((u >> 16) & 1u)) >> 16;
    return (unsigned short)r;
}
__device__ __forceinline__ float bf16_val(unsigned short h) {
    return __uint_as_float((unsigned)h << 16);
}

// Frag-tile layout: tile(row0=16 rows, k0=32 k) -> 64 lanes x 8 bf16, 1KB
// contiguous. lane = quad*16 + l16 holds (row = row0+l16, k = k0+quad*8+j).

// ---------------------------------------------------------------------------
// PREP v2: blocks [0,128) convert_W; [128,2176) charge_init.
// convert_F is GONE -- qk_proj v3 converts feat in LDS (kills 64MB round-trip).
__global__ __launch_bounds__(256) void prep(
        const float* __restrict__ feat, const float* __restrict__ Wq,
        const float* __restrict__ Wk, const float* __restrict__ cw,
        const float* __restrict__ cbias,
        unsigned short* __restrict__ Wqh, unsigned short* __restrict__ Wql,
        unsigned short* __restrict__ Wkh, unsigned short* __restrict__ Wkl,
        float* __restrict__ c0) {
    const int bid = blockIdx.x;
    const int tid = threadIdx.x;
    if (bid < 128) {
        // ---- convert_W: W[f][e] -> frag-tiled hi/lo (tile = 16 e x 32 f)
        const int mat = bid >> 6;
        const int g = (bid & 63) * 256 + tid;
        const int tile = g >> 6, lane = g & 63;
        const int ec = tile >> 5, fc = tile & 31;
        const int e = ec * 16 + (lane & 15);
        const int f0 = fc * 32 + (lane >> 4) * 8;
        const float* W = mat ? Wk : Wq;
        unsigned short* Th = mat ? Wkh : Wqh;
        unsigned short* Tl = mat ? Wkl : Wql;
        unsigned short hh[8], ll[8];
        #pragma unroll
        for (int j = 0; j < 8; ++j) {
            float v = W[(size_t)(f0 + j) * DE + e];
            hh[j] = bf16_hi(v); ll[j] = bf16_hi(v - bf16_val(hh[j]));
        }
        const size_t dst = (size_t)tile * 512 + lane * 8;
        *(ushort4*)&Th[dst]     = make_ushort4(hh[0], hh[1], hh[2], hh[3]);
        *(ushort4*)&Th[dst + 4] = make_ushort4(hh[4], hh[5], hh[6], hh[7]);
        *(ushort4*)&Tl[dst]     = make_ushort4(ll[0], ll[1], ll[2], ll[3]);
        *(ushort4*)&Tl[dst + 4] = make_ushort4(ll[4], ll[5], ll[6], ll[7]);
    } else {
        // ---- charge_init: c0 = sigmoid(F @ cw + cb), one wave per row
        const int wave = tid >> 6, lane = tid & 63;
        const int r = (bid - 128) * 4 + wave;
        const float* fr = feat + (size_t)r * FD;
        float s = 0.f;
        #pragma unroll
        for (int k = 0; k < 16; ++k) { int f = lane + 64 * k; s += fr[f] * cw[f]; }
        for (int off = 32; off > 0; off >>= 1) s += __shfl_xor(s, off);
        if (lane == 0) {
            float x = s + cbias[0];
            c0[r] = 1.f / (1.f + __expf(-x));
        }
    }
}

// ---------------------------------------------------------------------------
// QK_PROJ v3: feat read DIRECTLY (no Fh/Fl intermediates). Each block stages
// its 16 rows x 1024 f as bf16 hi/lo frag tiles in LDS (64KB), then runs the
// round-9 in-block 4-way K-split MFMA. The reduce stage REUSES the same 64KB
// LDS (fstage dead after K-loop; extra barrier separates) -> 2 blocks/CU.
__global__ __launch_bounds__(1024) void qk_proj(
        const float* __restrict__ feat,
        const unsigned short* __restrict__ Wqh, const unsigned short* __restrict__ Wql,
        const unsigned short* __restrict__ Wkh, const unsigned short* __restrict__ Wkl,
        unsigned short* __restrict__ Qh, unsigned short* __restrict__ Ql,
        unsigned short* __restrict__ Kh, unsigned short* __restrict__ Kl) {
    __shared__ f32x4 stage[4096];                       // 64KB, time-multiplexed
    unsigned short* fstage = (unsigned short*)stage;    // [0..16384) Fh, [16384..) Fl
    const int tid = threadIdx.x;
    const int w = tid >> 6, lane = tid & 63;
    const int quad = lane >> 4, l16 = lane & 15;
    const int blk = blockIdx.x;            // row-tile index (16 rows)
    const int mat = w >> 3, ech = (w >> 2) & 1, kch = w & 3;
    const unsigned short* Bh = mat ? Wkh : Wqh;
    const unsigned short* Bl = mat ? Wkl : Wql;

    // phase 0: stage 16 feat rows -> hi/lo frag tiles in LDS.
    // element (row rl, f): dst = (f>>5)*512 + (((f>>3)&3)*16 + rl)*8 + (f&7)
    // (identical mapping to the old convert_F).
    const float* fb = feat + (size_t)blk * 16 * FD;   // 16 contiguous rows
    #pragma unroll
    for (int it = 0; it < 4; ++it) {
        const int linear = it * 4096 + tid * 4;
        const int rl = linear >> 10, f = linear & 1023;
        const float4 a = *(const float4*)&fb[linear];
        ushort4 h, l;
        h.x = bf16_hi(a.x); l.x = bf16_hi(a.x - bf16_val(h.x));
        h.y = bf16_hi(a.y); l.y = bf16_hi(a.y - bf16_val(h.y));
        h.z = bf16_hi(a.z); l.z = bf16_hi(a.z - bf16_val(h.z));
        h.w = bf16_hi(a.w); l.w = bf16_hi(a.w - bf16_val(h.w));
        const int dst = (f >> 5) * 512 + (((f >> 3) & 3) * 16 + rl) * 8 + (f & 7);
        *(ushort4*)&fstage[dst]         = h;
        *(ushort4*)&fstage[16384 + dst] = l;
    }
    __syncthreads();

    f32x4 acc[4];
    #pragma unroll
    for (int c = 0; c < 4; ++c) acc[c] = (f32x4){0.f, 0.f, 0.f, 0.f};

    const int fc0 = kch * 8;
    #pragma unroll 2
    for (int f = 0; f < 8; ++f) {
        const int fc = fc0 + f;
        bf16x8 aH = *(const bf16x8*)&fstage[fc * 512 + lane * 8];
        bf16x8 aL = *(const bf16x8*)&fstage[16384 + fc * 512 + lane * 8];
        #pragma unroll
        for (int ct = 0; ct < 4; ++ct) {
            const size_t boff = ((size_t)((ech * 4 + ct) * 32 + fc) * 64 + lane) * 8;
            bf16x8 bH = *(const bf16x8*)&Bh[boff];
            bf16x8 bL = *(const bf16x8*)&Bl[boff];
            acc[ct] = __builtin_amdgcn_mfma_f32_16x16x32_bf16(aH, bH, acc[ct], 0, 0, 0);
            acc[ct] = __builtin_amdgcn_mfma_f32_16x16x32_bf16(aH, bL, acc[ct], 0, 0, 0);
            acc[ct] = __builtin_amdgcn_mfma_f32_16x16x32_bf16(aL, bH, acc[ct], 0, 0, 0);
        }
    }
    __syncthreads();   // fstage reads complete before stage overwrite

    // stage per-chunk partials (overlays fstage)
    #pragma unroll
    for (int ct = 0; ct < 4; ++ct)
        stage[(w * 4 + ct) * 64 + lane] = acc[ct];
    __syncthreads();

    // kc==0 waves: sum 4 chunks
    f32x4 red[4];
    const bool reducer = (kch == 0);
    if (reducer) {
        #pragma unroll
        for (int ct = 0; ct < 4; ++ct) {
            f32x4 s = stage[(w * 4 + ct) * 64 + lane];
            #pragma unroll
            for (int k = 1; k < 4; ++k) {
                const f32x4 t = stage[((w + k) * 4 + ct) * 64 + lane];
                s.x += t.x; s.y += t.y; s.z += t.z; s.w += t.w;
            }
            red[ct] = s;
        }
    }
    __syncthreads();

    unsigned short* lds16 = (unsigned short*)stage;   // first 16KB
    if (reducer) {
        #pragma unroll
        for (int ct = 0; ct < 4; ++ct) {
            const int e = (ech * 4 + ct) * 16 + l16;
            const int kce = e >> 5, q2 = (e >> 3) & 3, j2 = e & 7;
            #pragma unroll
            for (int reg = 0; reg < 4; ++reg) {
                const int rl = quad * 4 + reg;
                const float v = red[ct][reg];
                const unsigned short h = bf16_hi(v);
                const unsigned short l = bf16_hi(v - bf16_val(h));
                const int idx = (kce * 64 + q2 * 16 + rl) * 8 + j2;
                lds16[(mat * 2 + 0) * 2048 + idx] = h;
                lds16[(mat * 2 + 1) * 2048 + idx] = l;
            }
        }
    }
    __syncthreads();

    const int ch = tid >> 8, o = (tid & 255) * 8;
    const size_t gbase = (size_t)blk * 2048;
    unsigned short* const dsts[4] = {Qh, Ql, Kh, Kl};
    unsigned short* dst = dsts[ch] + gbase + o;
    *(ushort4*)&dst[0] = *(const ushort4*)&lds16[ch * 2048 + o];
    *(ushort4*)&dst[4] = *(const ushort4*)&lds16[ch * 2048 + o + 4];
}

// ---------------------------------------------------------------------------
// K1: baseH = f16((Q.K^T)/sqrt(128) + locality).
__global__ __launch_bounds__(256) void base_mfma(
        const unsigned short* __restrict__ Qh, const unsigned short* __restrict__ Ql,
        const unsigned short* __restrict__ Kh, const unsigned short* __restrict__ Kl,
        const float* __restrict__ d_ls, _Float16* __restrict__ baseH) {
    const int tid = threadIdx.x;
    const int w = tid >> 6, lane = tid & 63;
    const int quad = lane >> 4, l16 = lane & 15;
    const int b = blockIdx.z;
    const int i0 = blockIdx.y * 128, j0 = blockIdx.x * 128;
    const int trA0 = (b * NN + i0) / 16 + w * 2;
    const int trB0 = (b * NN + j0) / 16;

    f32x4 acc[2][8];
    #pragma unroll
    for (int a = 0; a < 2; ++a)
        #pragma unroll
        for (int c = 0; c < 8; ++c) acc[a][c] = (f32x4){0.f, 0.f, 0.f, 0.f};

    #pragma unroll
    for (int kc = 0; kc < 4; ++kc) {
        bf16x8 aH[2], aL[2];
        #pragma unroll
        for (int rt = 0; rt < 2; ++rt) {
            const size_t off = ((size_t)((trA0 + rt) * 4 + kc) * 64 + lane) * 8;
            aH[rt] = *(const bf16x8*)&Qh[off];
            aL[rt] = *(const bf16x8*)&Ql[off];
        }
        #pragma unroll
        for (int ct = 0; ct < 8; ++ct) {
            const size_t off = ((size_t)((trB0 + ct) * 4 + kc) * 64 + lane) * 8;
            bf16x8 bH = *(const bf16x8*)&Kh[off];
            bf16x8 bL = *(const bf16x8*)&Kl[off];
            #pragma unroll
            for (int rt = 0; rt < 2; ++rt) {
                acc[rt][ct] = __builtin_amdgcn_mfma_f32_16x16x32_bf16(aH[rt], bH, acc[rt][ct], 0, 0, 0);
                acc[rt][ct] = __builtin_amdgcn_mfma_f32_16x16x32_bf16(aH[rt], bL, acc[rt][ct], 0, 0, 0);
                acc[rt][ct] = __builtin_amdgcn_mfma_f32_16x16x32_bf16(aL[rt], bH, acc[rt][ct], 0, 0, 0);
            }
        }
    }
    const float ls = d_ls[0];
    const float rs = 0.08838834764831845f;  // 1/sqrt(128)
    #pragma unroll
    for (int rt = 0; rt < 2; ++rt)
        #pragma unroll
        for (int reg = 0; reg < 4; ++reg) {
            const int i = i0 + w * 32 + rt * 16 + quad * 4 + reg;
            _Float16* brow = baseH + ((size_t)b * NN + i) * NN;
            #pragma unroll
            for (int ct = 0; ct < 8; ++ct) {
                const int j = j0 + ct * 16 + l16;
                const float dist = fmaxf(fabsf((float)(i - j)), 1.0f);
                brow[j] = (_Float16)(acc[rt][ct][reg] * rs + ls / dist);
            }
        }
}

// ---------------------------------------------------------------------------
// K2 v4 (best measured, round 9 = 276us): one ROW per block-iteration,
// 8 COLUMNS per thread; next-row prefetch; hoisted column charges.
template <int T, bool WO>
__global__ __launch_bounds__(256) void step_pass(
        const _Float16* __restrict__ base, const float* __restrict__ charge,
        const float* __restrict__ d_ss, float* __restrict__ P,
        float* __restrict__ out) {
    constexpr int TS = T > 0 ? T : 1;
    __shared__ float wsum[2][4];
    const int tid = threadIdx.x;
    const int w = tid >> 6, lane = tid & 63;
    const int blk = blockIdx.x;
    const int b = blk >> 8;               // 256 blocks per batch
    const int r0 = (blk & 255) * 8;       // 8 rows per block
    const float ss = d_ss[0];
    const size_t cb = (size_t)b << 11;
    const int c0 = tid * 8;               // this thread's 8 columns

    float cjv[TS][8];
    #pragma unroll
    for (int u = 0; u < T; ++u) {
        const float* s = &charge[(size_t)(u + 1) * BN + cb + c0];
        const float4 a0 = *(const float4*)&s[0];
        const float4 a1 = *(const float4*)&s[4];
        cjv[u][0] = a0.x; cjv[u][1] = a0.y; cjv[u][2] = a0.z; cjv[u][3] = a0.w;
        cjv[u][4] = a1.x; cjv[u][5] = a1.y; cjv[u][6] = a1.z; cjv[u][7] = a1.w;
    }

    float col_acc[8];
    if (!WO) {
        #pragma unroll
        for (int j = 0; j < 8; ++j) col_acc[j] = 0.f;
    }

    const _Float16* bp = base + (cb + r0) * NN + c0;
    f16x8 hv = *(const f16x8*)bp;

    #pragma unroll
    for (int r = 0; r < 8; ++r) {
        f16x8 hvn;
        if (r < 7) hvn = *(const f16x8*)(bp + (size_t)(r + 1) * NN);
        const size_t ri = cb + r0 + r;
        float ci[TS];
        #pragma unroll
        for (int u = 0; u < T; ++u)
            ci[u] = charge[(size_t)(u + 1) * BN + ri] * ss;

        float x[8];
        float ps = 0.f;
        #pragma unroll
        for (int j = 0; j < 8; ++j) {
            float m = 1.f;
            #pragma unroll
            for (int u = 0; u < T; ++u) m += ci[u] * cjv[u][j];
            const float v = __expf((float)hv[j] * m);
            x[j] = v;
            ps += v;
        }
        #pragma unroll
        for (int off = 32; off > 0; off >>= 1) ps += __shfl_xor(ps, off);
        if (lane == 0) wsum[r & 1][w] = ps;
        __syncthreads();
        const float inv = 1.f / (wsum[r & 1][0] + wsum[r & 1][1] +
                                 wsum[r & 1][2] + wsum[r & 1][3]);

        if (WO) {
            float4 o0 = {x[0] * inv, x[1] * inv, x[2] * inv, x[3] * inv};
            float4 o1 = {x[4] * inv, x[5] * inv, x[6] * inv, x[7] * inv};
            float* op = &out[ri * NN + c0];
            *(float4*)&op[0] = o0;
            *(float4*)&op[4] = o1;
        } else {
            #pragma unroll
            for (int j = 0; j < 8; ++j) col_acc[j] += x[j] * inv;
        }
        hv = hvn;
    }

    if (!WO) {
        float* prow = P + (size_t)blk * NN + c0;
        *(float4*)&prow[0] = *(float4*)&col_acc[0];
        *(float4*)&prow[4] = *(float4*)&col_acc[4];
    }
}

// ---------------------------------------------------------------------------
// K3: received[col] = sum over 256 block partials; charge update.
__global__ __launch_bounds__(256) void charge_reduce(
        const float* __restrict__ P, const float* __restrict__ d_decay,
        const float* __restrict__ c_prev, float* __restrict__ c_next) {
    const int b = blockIdx.x >> 3;
    const int col = ((blockIdx.x & 7) << 8) + threadIdx.x;
    const float* p = P + ((size_t)b * 256) * NN + col;
    float s = 0.f;
    #pragma unroll 8
    for (int r = 0; r < 256; ++r) s += p[(size_t)r * NN];
    const int gi = (b << 11) + col;
    const float sg = 1.f / (1.f + __expf(1.f - s));
    c_next[gi] = c_prev[gi] * (1.f - d_decay[0] * sg);
}

// ---------------------------------------------------------------------------
extern "C" void kernel_launch(void* const* d_in, const int* in_sizes, int n_in,
                              void* d_out, int out_size, void* d_ws, size_t ws_size,
                              hipStream_t stream) {
    const float* feat  = (const float*)d_in[0];
    const float* Wq    = (const float*)d_in[1];
    const float* Wk    = (const float*)d_in[2];
    const float* cw    = (const float*)d_in[3];
    const float* cb    = (const float*)d_in[4];
    const float* ls    = (const float*)d_in[5];
    const float* ssp   = (const float*)d_in[6];
    const float* decay = (const float*)d_in[7];

    float* ws   = (float*)d_ws;
    unsigned short* qkhl = (unsigned short*)(ws + QKHL_OFF);
    unsigned short* Qh = qkhl;
    unsigned short* Ql = qkhl + (size_t)BN * DE;
    unsigned short* Kh = qkhl + (size_t)2 * BN * DE;
    unsigned short* Kl = qkhl + (size_t)3 * BN * DE;
    unsigned short* Wqh = (unsigned short*)(ws + WSW_OFF);
    unsigned short* Wql = Wqh + (size_t)DE * FD;
    unsigned short* Wkh = Wqh + (size_t)2 * DE * FD;
    unsigned short* Wkl = Wqh + (size_t)3 * DE * FD;
    float* charge = ws + C_OFF;
    // baseH (f16) overlays [0..FH_OFF) -- Wsw dead after qk_proj
    _Float16* baseH = (_Float16*)(ws + WSW_OFF);
    float* P      = ws + FH_OFF;
    float* out    = (float*)d_out;

    prep<<<2176, 256, 0, stream>>>(feat, Wq, Wk, cw, cb,
                                   Wqh, Wql, Wkh, Wkl, charge);
    qk_proj<<<512, 1024, 0, stream>>>(feat, Wqh, Wql, Wkh, Wkl,
                                      Qh, Ql, Kh, Kl);
    base_mfma<<<dim3(NN / 128, NN / 128, NB), 256, 0, stream>>>(
        Qh, Ql, Kh, Kl, ls, baseH);

    step_pass<0, false><<<1024, 256, 0, stream>>>(baseH, charge, ssp, P, nullptr);
    charge_reduce<<<32, 256, 0, stream>>>(P, decay, charge, charge + (size_t)BN);
    step_pass<1, false><<<1024, 256, 0, stream>>>(baseH, charge, ssp, P, nullptr);
    charge_reduce<<<32, 256, 0, stream>>>(P, decay, charge + (size_t)BN, charge + (size_t)2 * BN);
    step_pass<2, false><<<1024, 256, 0, stream>>>(baseH, charge, ssp, P, nullptr);
    charge_reduce<<<32, 256, 0, stream>>>(P, decay, charge + (size_t)2 * BN, charge + (size_t)3 * BN);
    step_pass<3, false><<<1024, 256, 0, stream>>>(baseH, charge, ssp, P, nullptr);
    charge_reduce<<<32, 256, 0, stream>>>(P, decay, charge + (size_t)3 * BN, charge + (size_t)4 * BN);
    step_pass<4, true><<<1024, 256, 0, stream>>>(baseH, charge, ssp, nullptr, out);
}